// Round 8
// baseline (84.977 us; speedup 1.0000x reference)
//
#include <hip/hip_runtime.h>

#define MODS 4
#define CH   128
#define NHD  4
#define HDIM 32
#define NTOK 1728
#define NG   (NTOK/4)
#define NKEY (MODS*NTOK)        // 6912
#define NT   27                 // 64-key tiles per 1728-key stream
// Q is pre-scaled by 1/sqrt(32) * log2(e) so softmax is exp2(S) directly.
#define QSC (0.17677669529663687f * 1.4426950408889634f)

#ifndef __has_builtin
#define __has_builtin(x) 0
#endif
#if __has_builtin(__builtin_amdgcn_exp2f)
#define EXP2(x) __builtin_amdgcn_exp2f(x)
#else
#define EXP2(x) __expf(0.69314718055994531f * (x))
#endif

typedef __bf16 bf16x8 __attribute__((ext_vector_type(8)));
typedef float  f32x16 __attribute__((ext_vector_type(16)));
typedef unsigned int u32x4 __attribute__((ext_vector_type(4)));

__device__ inline bf16x8 ldb8(const unsigned short* p) {
    return *reinterpret_cast<const bf16x8*>(p);
}
__device__ inline unsigned int pkbf(float a, float b) {
    unsigned short ua = __builtin_bit_cast(unsigned short, (__bf16)a);
    unsigned short ub = __builtin_bit_cast(unsigned short, (__bf16)b);
    return (unsigned int)ua | ((unsigned int)ub << 16);
}
// async global->LDS, 16B per lane; LDS dest = uniform base + lane*16
__device__ inline void glds16(const unsigned short* g, unsigned short* l) {
    __builtin_amdgcn_global_load_lds(
        (const __attribute__((address_space(1))) unsigned int*)(g),
        (__attribute__((address_space(3))) unsigned int*)(l), 16, 0, 0);
}

// ---------------------------------------------------------------------------
// Kernel 1: LDS-tiled QKV projection (fp32 math, bf16 out), c-split halves.
// Qb/Kb: bf16 [m][h][n][32] (Q pre-scaled by QSC).
// V2: bf16 [h][32d][key], keys fragment-ordered per 16-window:
//     4-key group at offset {0,4,8,12} stored at position {0,8,4,12}.
// ---------------------------------------------------------------------------
__global__ __launch_bounds__(256) void proj_kernel(
    const float* __restrict__ f0, const float* __restrict__ f1,
    const float* __restrict__ f2, const float* __restrict__ f3,
    const float* __restrict__ Wq, const float* __restrict__ Wk,
    const float* __restrict__ Wv,
    unsigned short* __restrict__ Qb, unsigned short* __restrict__ Kb,
    unsigned short* __restrict__ V2)
{
    __shared__ __align__(16) float Wt[64][68];   // 17 KB
    __shared__ __align__(16) float fs[64][68];   // 17 KB

    const int tid = threadIdx.x;
    const int bid = blockIdx.x;
    const int tm  = bid / 54;
    const int rem = bid % 54;
    const int oh  = rem & 1;
    const int nt  = rem >> 1;
    const int t   = tm >> 2, m = tm & 3;
    const int nb  = nt * 64;

    const float* fsrc = (m == 0) ? f0 : (m == 1) ? f1 : (m == 2) ? f2 : f3;
    const float* W    = ((t == 0) ? Wq : (t == 1) ? Wk : Wv) + (size_t)m * CH * CH;

    const int o0 = (tid >> 4) * 4, nn0 = (tid & 15) * 4;
    float acc[4][4] = {};

    for (int ch = 0; ch < 2; ++ch) {
        if (ch) __syncthreads();
        {
            const int o = tid & 63, c4b = tid >> 6;
            #pragma unroll
            for (int j = 0; j < 4; ++j) {
                const int c4 = c4b + 4 * j;
                float4 wv = *reinterpret_cast<const float4*>(
                    W + (size_t)(oh * 64 + o) * CH + ch * 64 + c4 * 4);
                Wt[c4*4+0][o] = wv.x; Wt[c4*4+1][o] = wv.y;
                Wt[c4*4+2][o] = wv.z; Wt[c4*4+3][o] = wv.w;
            }
        }
        {
            const int nchunk = tid & 15, cb = tid >> 4;
            #pragma unroll
            for (int j = 0; j < 4; ++j) {
                const int c = cb + 16 * j;
                float4 v = *reinterpret_cast<const float4*>(
                    fsrc + (size_t)(ch * 64 + c) * NTOK + nb + nchunk * 4);
                *reinterpret_cast<float4*>(&fs[c][nchunk * 4]) = v;
            }
        }
        __syncthreads();
        #pragma unroll 4
        for (int c = 0; c < 64; ++c) {
            float4 wv = *reinterpret_cast<const float4*>(&Wt[c][o0]);
            float4 fv = *reinterpret_cast<const float4*>(&fs[c][nn0]);
            acc[0][0] = fmaf(wv.x, fv.x, acc[0][0]); acc[0][1] = fmaf(wv.x, fv.y, acc[0][1]);
            acc[0][2] = fmaf(wv.x, fv.z, acc[0][2]); acc[0][3] = fmaf(wv.x, fv.w, acc[0][3]);
            acc[1][0] = fmaf(wv.y, fv.x, acc[1][0]); acc[1][1] = fmaf(wv.y, fv.y, acc[1][1]);
            acc[1][2] = fmaf(wv.y, fv.z, acc[1][2]); acc[1][3] = fmaf(wv.y, fv.w, acc[1][3]);
            acc[2][0] = fmaf(wv.z, fv.x, acc[2][0]); acc[2][1] = fmaf(wv.z, fv.y, acc[2][1]);
            acc[2][2] = fmaf(wv.z, fv.z, acc[2][2]); acc[2][3] = fmaf(wv.z, fv.w, acc[2][3]);
            acc[3][0] = fmaf(wv.w, fv.x, acc[3][0]); acc[3][1] = fmaf(wv.w, fv.y, acc[3][1]);
            acc[3][2] = fmaf(wv.w, fv.z, acc[3][2]); acc[3][3] = fmaf(wv.w, fv.w, acc[3][3]);
        }
    }

    const int og0 = oh * 64 + o0;
    const int h = og0 >> 5, d0 = og0 & 31;
    const int ng = nb + nn0;
    if (t == 2) {
        const int off = ng & 15;                      // 0,4,8,12
        const int ng2 = (ng & ~15) + ((off & 4) << 1) + ((off & 8) >> 1);
        #pragma unroll
        for (int i = 0; i < 4; ++i) {
            ushort4 pk;
            pk.x = __builtin_bit_cast(unsigned short, (__bf16)acc[i][0]);
            pk.y = __builtin_bit_cast(unsigned short, (__bf16)acc[i][1]);
            pk.z = __builtin_bit_cast(unsigned short, (__bf16)acc[i][2]);
            pk.w = __builtin_bit_cast(unsigned short, (__bf16)acc[i][3]);
            *reinterpret_cast<ushort4*>(V2 + (size_t)(h * HDIM + d0 + i) * NKEY + m * NTOK + ng2) = pk;
        }
    } else {
        const float sc = (t == 0) ? QSC : 1.0f;
        unsigned short* base = ((t == 0) ? Qb : Kb)
            + (((size_t)(m * NHD + h)) * NTOK + ng) * HDIM + d0;
        #pragma unroll
        for (int j = 0; j < 4; ++j) {
            unsigned short* row = base + (size_t)j * HDIM;
            *reinterpret_cast<unsigned int*>(row)     = pkbf(acc[0][j] * sc, acc[1][j] * sc);
            *reinterpret_cast<unsigned int*>(row + 2) = pkbf(acc[2][j] * sc, acc[3][j] * sc);
        }
    }
}

// ---------------------------------------------------------------------------
// Kernel 2: MFMA cross-modal attention, 864 blocks x 4 waves (256 thr).
// Block = (h, ko, qb 0..107); wave w: qslot=w&1 (qtile = qb*2+qslot),
// ks=w>>1 (inner key stream, modality km=2ko+ks).
// Counted-vmcnt raw-barrier pipeline (T3/T4): each wave issues its own
// 4 glds per 64-key tile (depth-2 prefetch, 8 outstanding); per tile:
// vmcnt(4)+barrier -> compute -> lgkmcnt(0)+barrier -> stage t+2.
// Per-wave wait + barrier => all 16 glds of tile t visible collectively.
// Swizzles (verified R7, conflict-free): K chunk ^= (key>>1)&3,
// V chunk ^= d&7, pre-applied on glds SOURCE, involution on ds_read.
// MFMA pairing identical to verified R4-R7. Max-free exp2 softmax.
// ---------------------------------------------------------------------------
__global__ __launch_bounds__(256) void attn_kernel(
    const unsigned short* __restrict__ Qb, const unsigned short* __restrict__ Kb,
    const unsigned short* __restrict__ V2,
    float* __restrict__ accT, float* __restrict__ sR)
{
    __shared__ __align__(16) unsigned short smAll[2][2][2][2048]; // [buf][ks][K/V] 32 KB
    __shared__ __align__(16) float sL[2][2][2][32];               // [qslot][ks][hi][q] 1 KB

    const int tid  = threadIdx.x;
    const int lane = tid & 63;
    const int w    = tid >> 6;        // 0..3
    const int qslot = w & 1;
    const int ks    = w >> 1;
    const int l31  = lane & 31;
    const int hi   = lane >> 5;

    const int bid  = blockIdx.x;
    const int slot = bid & 7;              // XCD slot
    const int h    = slot >> 1;
    const int ko   = slot & 1;
    const int qb   = bid >> 3;             // 0..107
    const int qtile = qb * 2 + qslot;      // 0..215
    const int qg0  = qtile * 32;
    const int im   = qg0 / NTOK;
    const int n0   = qg0 % NTOK;
    const int km   = ko * 2 + ks;

    // Q fragments (pre-scaled by QSC)
    const unsigned short* qp = Qb + (((size_t)(im * NHD + h)) * NTOK + n0 + l31) * HDIM + hi * 8;
    const bf16x8 qf0 = ldb8(qp);
    const bf16x8 qf1 = ldb8(qp + 16);

    // --- staging sources (this wave's 4 glds per tile, inverse-swizzled) ---
    const int rk0 = qslot * 32 + (lane >> 2);            // K rows [qslot half]
    const int ck0 = (lane & 3) ^ ((rk0 >> 1) & 3);
    const unsigned short* gK0 = Kb + (((size_t)(km * NHD + h)) * NTOK + rk0) * HDIM + ck0 * 8;
    const int rk1 = rk0 + 16;
    const int ck1 = (lane & 3) ^ ((rk1 >> 1) & 3);
    const unsigned short* gK1 = Kb + (((size_t)(km * NHD + h)) * NTOK + rk1) * HDIM + ck1 * 8;
    const int dv0 = qslot * 16 + (lane >> 3);            // V d-rows [qslot half]
    const int cv0 = (lane & 7) ^ (dv0 & 7);
    const unsigned short* gV0 = V2 + ((size_t)(h * HDIM + dv0)) * NKEY + km * NTOK + cv0 * 8;
    const int dv1 = dv0 + 8;
    const int cv1 = (lane & 7) ^ (dv1 & 7);
    const unsigned short* gV1 = V2 + ((size_t)(h * HDIM + dv1)) * NKEY + km * NTOK + cv1 * 8;

    // --- LDS read offsets (shorts), swizzle involution applied ---
    const int f31 = (l31 >> 1) & 3;
    const int kA0 = l31 * 32 + ((hi ^ f31) << 3);
    const int kB0 = l31 * 32 + (((2 + hi) ^ f31) << 3);
    const int vbase = l31 * 64;
    const int x7 = l31 & 7;

    f32x16 o_acc;
    #pragma unroll
    for (int r = 0; r < 16; ++r) o_acc[r] = 0.f;
    float s_part = 0.f;

    // stage tile tt into buffer bb (4 glds, program-ordered per wave)
    #define STAGE(tt, bb) do {                                              \
        unsigned short* _k = &smAll[bb][ks][0][0];                          \
        glds16(gK0 + (size_t)(tt) * 2048, _k + (qslot * 32) * 32);          \
        glds16(gK1 + (size_t)(tt) * 2048, _k + (qslot * 32 + 16) * 32);     \
        unsigned short* _v = &smAll[bb][ks][1][0];                          \
        glds16(gV0 + (size_t)(tt) * 64,  _v + (qslot * 16) * 64);           \
        glds16(gV1 + (size_t)(tt) * 64,  _v + (qslot * 16 + 8) * 64);       \
    } while (0)

    STAGE(0, 0);
    STAGE(1, 1);

    for (int t = 0; t < NT; ++t) {
        // tile t ready: wait own 4 oldest glds, then rendezvous
        if (t < NT - 1) asm volatile("s_waitcnt vmcnt(4)" ::: "memory");
        else            asm volatile("s_waitcnt vmcnt(0)" ::: "memory");
        __builtin_amdgcn_sched_barrier(0);
        __builtin_amdgcn_s_barrier();
        __builtin_amdgcn_sched_barrier(0);

        const unsigned short* Kl = &smAll[t & 1][ks][0][0];
        const unsigned short* Vl = &smAll[t & 1][ks][1][0];

        #pragma unroll
        for (int st = 0; st < 2; ++st) {
            bf16x8 k0 = ldb8(Kl + st * 1024 + kA0);
            bf16x8 k1 = ldb8(Kl + st * 1024 + kB0);
            f32x16 c;
            #pragma unroll
            for (int r = 0; r < 16; ++r) c[r] = 0.f;
            c = __builtin_amdgcn_mfma_f32_32x32x16_bf16(k0, qf0, c, 0, 0, 0);
            c = __builtin_amdgcn_mfma_f32_32x32x16_bf16(k1, qf1, c, 0, 0, 0);

            float e[16];
            #pragma unroll
            for (int r = 0; r < 16; ++r) { e[r] = EXP2(c[r]); s_part += e[r]; }
            bf16x8 pa0, pa1;
            #pragma unroll
            for (int j = 0; j < 8; ++j) { pa0[j] = (__bf16)e[j]; pa1[j] = (__bf16)e[8 + j]; }

            bf16x8 v0 = ldb8(Vl + vbase + (((4 * st + hi)     ^ x7) << 3));
            bf16x8 v1 = ldb8(Vl + vbase + (((4 * st + 2 + hi) ^ x7) << 3));

            o_acc = __builtin_amdgcn_mfma_f32_32x32x16_bf16(pa0, v0, o_acc, 0, 0, 0);
            o_acc = __builtin_amdgcn_mfma_f32_32x32x16_bf16(pa1, v1, o_acc, 0, 0, 0);
        }

        // all waves done reading buf[t&1]; then refill it with tile t+2
        asm volatile("s_waitcnt lgkmcnt(0)" ::: "memory");
        __builtin_amdgcn_sched_barrier(0);
        __builtin_amdgcn_s_barrier();
        __builtin_amdgcn_sched_barrier(0);
        if (t + 2 < NT) STAGE(t + 2, t & 1);
    }
    #undef STAGE

    // --- epilogue: combine ks pair in LDS [64 q][33] (padded), transpose ---
    __syncthreads();
    float* accf = (float*)&smAll[0][0][0][0];    // 64*33*4 = 8.4 KB (reuse)
    if (ks == 1) {
        #pragma unroll
        for (int r = 0; r < 16; ++r) {
            const int qrow = (r & 3) + 8 * (r >> 2) + 4 * hi;
            accf[(qslot * 32 + qrow) * 33 + l31] = o_acc[r];
        }
    }
    sL[qslot][ks][hi][l31] = s_part;
    __syncthreads();
    if (ks == 0) {
        #pragma unroll
        for (int r = 0; r < 16; ++r) {
            const int qrow = (r & 3) + 8 * (r >> 2) + 4 * hi;
            accf[(qslot * 32 + qrow) * 33 + l31] += o_acc[r];
        }
    }
    __syncthreads();
    {
        const int q  = tid & 63;
        const int dq = tid >> 6;      // 0..3
        #pragma unroll
        for (int j = 0; j < 8; ++j) {
            const int d = dq * 8 + j;
            accT[((size_t)((ko * 4 + h) * HDIM + d)) * NKEY + (size_t)qb * 64 + q]
                = accf[q * 33 + d];
        }
        if (tid < 64) {
            const int qs = tid >> 5, ql = tid & 31;
            float st = (sL[qs][0][0][ql] + sL[qs][0][1][ql])
                     + (sL[qs][1][0][ql] + sL[qs][1][1][ql]);
            sR[((size_t)(ko * 4 + h)) * NKEY + (size_t)qb * 64 + tid] = st;
        }
    }
}

// ---------------------------------------------------------------------------
// Kernel 3: combine outer key halves + normalize + modality-sum.
// ---------------------------------------------------------------------------
__global__ __launch_bounds__(256) void norm_kernel(
    const float* __restrict__ accT, const float* __restrict__ sR,
    float* __restrict__ fused)
{
    const int idx = blockIdx.x * 256 + threadIdx.x;  // 0 .. 128*1728-1
    const int c = idx / NTOK;
    const int n = idx % NTOK;
    const int h = c >> 5;
    float acc = 0.f;
    #pragma unroll
    for (int imq = 0; imq < MODS; ++imq) {
        const size_t q = (size_t)imq * NTOK + n;
        const float s = sR[(size_t)h * NKEY + q] + sR[(size_t)(4 + h) * NKEY + q];
        const float a = accT[(size_t)c * NKEY + q] + accT[(size_t)(c + 128) * NKEY + q];
        acc = fmaf(a, 1.0f / s, acc);
    }
    fused[idx] = acc;
}

// ---------------------------------------------------------------------------
// Kernel 4: out-proj (Wout @ fused) + BatchNorm(eval) + ReLU, 2 tokens/thread
// ---------------------------------------------------------------------------
__global__ __launch_bounds__(256) void outproj_kernel(
    const float* __restrict__ fused, const float* __restrict__ Wout,
    const float* __restrict__ gamma, const float* __restrict__ beta,
    const float* __restrict__ mean,  const float* __restrict__ var,
    float* __restrict__ out)
{
    const int idx = blockIdx.x * 256 + threadIdx.x;  // 0 .. 128*864-1
    const int n2 = idx % (NTOK / 2);
    const int o  = idx / (NTOK / 2);
    const float* W     = Wout + (size_t)o * CH;
    const float* fbase = fused + n2 * 2;
    float a0 = 0.f, a1 = 0.f;
    #pragma unroll 8
    for (int c = 0; c < CH; c += 4) {
        float4 w4 = *reinterpret_cast<const float4*>(W + c);
        float2 r0 = *reinterpret_cast<const float2*>(fbase + (size_t)(c + 0) * NTOK);
        float2 r1 = *reinterpret_cast<const float2*>(fbase + (size_t)(c + 1) * NTOK);
        float2 r2 = *reinterpret_cast<const float2*>(fbase + (size_t)(c + 2) * NTOK);
        float2 r3 = *reinterpret_cast<const float2*>(fbase + (size_t)(c + 3) * NTOK);
        a0 = fmaf(w4.x, r0.x, a0); a0 = fmaf(w4.y, r1.x, a0);
        a0 = fmaf(w4.z, r2.x, a0); a0 = fmaf(w4.w, r3.x, a0);
        a1 = fmaf(w4.x, r0.y, a1); a1 = fmaf(w4.y, r1.y, a1);
        a1 = fmaf(w4.z, r2.y, a1); a1 = fmaf(w4.w, r3.y, a1);
    }
    float inv = gamma[o] * rsqrtf(var[o] + 1e-5f);
    float sh  = fmaf(-mean[o], inv, beta[o]);
    float2 y;
    y.x = fmaxf(fmaf(a0, inv, sh), 0.f);
    y.y = fmaxf(fmaf(a1, inv, sh), 0.f);
    *reinterpret_cast<float2*>(out + (size_t)o * NTOK + n2 * 2) = y;
}

// ---------------------------------------------------------------------------
extern "C" void kernel_launch(void* const* d_in, const int* in_sizes, int n_in,
                              void* d_out, int out_size, void* d_ws, size_t ws_size,
                              hipStream_t stream)
{
    const float* f0    = (const float*)d_in[0];
    const float* f1    = (const float*)d_in[1];
    const float* f2    = (const float*)d_in[2];
    const float* f3    = (const float*)d_in[3];
    const float* Wq    = (const float*)d_in[4];
    const float* Wk    = (const float*)d_in[5];
    const float* Wv    = (const float*)d_in[6];
    const float* Wout  = (const float*)d_in[7];
    const float* gamma = (const float*)d_in[8];
    const float* beta  = (const float*)d_in[9];
    const float* mean  = (const float*)d_in[10];
    const float* var   = (const float*)d_in[11];
    float* out = (float*)d_out;

    const size_t QKV = (size_t)MODS * NHD * NTOK * HDIM;   // 884736 elems
    unsigned short* Qb = (unsigned short*)d_ws;
    unsigned short* Kb = Qb + QKV;
    unsigned short* V2 = Kb + QKV;
    float* accT  = (float*)(V2 + QKV);          // [256 rows][6912 q] f32
    float* sR    = accT + (size_t)2 * NHD * HDIM * NKEY;   // [8][6912]
    float* fused = sR + (size_t)2 * NHD * NKEY;            // [CH][NTOK]

    proj_kernel<<<648, 256, 0, stream>>>(f0, f1, f2, f3, Wq, Wk, Wv, Qb, Kb, V2);
    attn_kernel<<<864, 256, 0, stream>>>(Qb, Kb, V2, accT, sR);
    norm_kernel<<<(CH * NTOK) / 256, 256, 0, stream>>>(accT, sR, fused);
    outproj_kernel<<<(CH * NTOK / 2) / 256, 256, 0, stream>>>(
        fused, Wout, gamma, beta, mean, var, out);
}

// Round 9
// 79.382 us; speedup vs baseline: 1.0705x; 1.0705x over previous
//
#include <hip/hip_runtime.h>

#define MODS 4
#define CH   128
#define NHD  4
#define HDIM 32
#define NTOK 1728
#define NG   (NTOK/4)
#define NKEY (MODS*NTOK)        // 6912
#define NT   27                 // 64-key tiles per 1728-key stream
// Q is pre-scaled by 1/sqrt(32) * log2(e) so softmax is exp2(S) directly.
#define QSC (0.17677669529663687f * 1.4426950408889634f)

#ifndef __has_builtin
#define __has_builtin(x) 0
#endif
#if __has_builtin(__builtin_amdgcn_exp2f)
#define EXP2(x) __builtin_amdgcn_exp2f(x)
#else
#define EXP2(x) __expf(0.69314718055994531f * (x))
#endif

typedef __bf16 bf16x8 __attribute__((ext_vector_type(8)));
typedef float  f32x16 __attribute__((ext_vector_type(16)));
typedef unsigned int u32x4 __attribute__((ext_vector_type(4)));

__device__ inline bf16x8 ldb8(const unsigned short* p) {
    return *reinterpret_cast<const bf16x8*>(p);
}
__device__ inline unsigned int pkbf(float a, float b) {
    unsigned short ua = __builtin_bit_cast(unsigned short, (__bf16)a);
    unsigned short ub = __builtin_bit_cast(unsigned short, (__bf16)b);
    return (unsigned int)ua | ((unsigned int)ub << 16);
}
// async global->LDS, 16B per lane; LDS dest = uniform base + lane*16
__device__ inline void glds16(const unsigned short* g, unsigned short* l) {
    __builtin_amdgcn_global_load_lds(
        (const __attribute__((address_space(1))) unsigned int*)(g),
        (__attribute__((address_space(3))) unsigned int*)(l), 16, 0, 0);
}

// ---------------------------------------------------------------------------
// Kernel 1: LDS-tiled QKV projection (fp32 math, bf16 out), c-split halves.
// Qb/Kb: bf16 [m][h][n][32] (Q pre-scaled by QSC).
// V2: bf16 [h][32d][key], keys fragment-ordered per 16-window:
//     4-key group at offset {0,4,8,12} stored at position {0,8,4,12}.
// ---------------------------------------------------------------------------
__global__ __launch_bounds__(256) void proj_kernel(
    const float* __restrict__ f0, const float* __restrict__ f1,
    const float* __restrict__ f2, const float* __restrict__ f3,
    const float* __restrict__ Wq, const float* __restrict__ Wk,
    const float* __restrict__ Wv,
    unsigned short* __restrict__ Qb, unsigned short* __restrict__ Kb,
    unsigned short* __restrict__ V2)
{
    __shared__ __align__(16) float Wt[64][68];   // 17 KB
    __shared__ __align__(16) float fs[64][68];   // 17 KB

    const int tid = threadIdx.x;
    const int bid = blockIdx.x;
    const int tm  = bid / 54;
    const int rem = bid % 54;
    const int oh  = rem & 1;
    const int nt  = rem >> 1;
    const int t   = tm >> 2, m = tm & 3;
    const int nb  = nt * 64;

    const float* fsrc = (m == 0) ? f0 : (m == 1) ? f1 : (m == 2) ? f2 : f3;
    const float* W    = ((t == 0) ? Wq : (t == 1) ? Wk : Wv) + (size_t)m * CH * CH;

    const int o0 = (tid >> 4) * 4, nn0 = (tid & 15) * 4;
    float acc[4][4] = {};

    for (int ch = 0; ch < 2; ++ch) {
        if (ch) __syncthreads();
        {
            const int o = tid & 63, c4b = tid >> 6;
            #pragma unroll
            for (int j = 0; j < 4; ++j) {
                const int c4 = c4b + 4 * j;
                float4 wv = *reinterpret_cast<const float4*>(
                    W + (size_t)(oh * 64 + o) * CH + ch * 64 + c4 * 4);
                Wt[c4*4+0][o] = wv.x; Wt[c4*4+1][o] = wv.y;
                Wt[c4*4+2][o] = wv.z; Wt[c4*4+3][o] = wv.w;
            }
        }
        {
            const int nchunk = tid & 15, cb = tid >> 4;
            #pragma unroll
            for (int j = 0; j < 4; ++j) {
                const int c = cb + 16 * j;
                float4 v = *reinterpret_cast<const float4*>(
                    fsrc + (size_t)(ch * 64 + c) * NTOK + nb + nchunk * 4);
                *reinterpret_cast<float4*>(&fs[c][nchunk * 4]) = v;
            }
        }
        __syncthreads();
        #pragma unroll 4
        for (int c = 0; c < 64; ++c) {
            float4 wv = *reinterpret_cast<const float4*>(&Wt[c][o0]);
            float4 fv = *reinterpret_cast<const float4*>(&fs[c][nn0]);
            acc[0][0] = fmaf(wv.x, fv.x, acc[0][0]); acc[0][1] = fmaf(wv.x, fv.y, acc[0][1]);
            acc[0][2] = fmaf(wv.x, fv.z, acc[0][2]); acc[0][3] = fmaf(wv.x, fv.w, acc[0][3]);
            acc[1][0] = fmaf(wv.y, fv.x, acc[1][0]); acc[1][1] = fmaf(wv.y, fv.y, acc[1][1]);
            acc[1][2] = fmaf(wv.y, fv.z, acc[1][2]); acc[1][3] = fmaf(wv.y, fv.w, acc[1][3]);
            acc[2][0] = fmaf(wv.z, fv.x, acc[2][0]); acc[2][1] = fmaf(wv.z, fv.y, acc[2][1]);
            acc[2][2] = fmaf(wv.z, fv.z, acc[2][2]); acc[2][3] = fmaf(wv.z, fv.w, acc[2][3]);
            acc[3][0] = fmaf(wv.w, fv.x, acc[3][0]); acc[3][1] = fmaf(wv.w, fv.y, acc[3][1]);
            acc[3][2] = fmaf(wv.w, fv.z, acc[3][2]); acc[3][3] = fmaf(wv.w, fv.w, acc[3][3]);
        }
    }

    const int og0 = oh * 64 + o0;
    const int h = og0 >> 5, d0 = og0 & 31;
    const int ng = nb + nn0;
    if (t == 2) {
        const int off = ng & 15;                      // 0,4,8,12
        const int ng2 = (ng & ~15) + ((off & 4) << 1) + ((off & 8) >> 1);
        #pragma unroll
        for (int i = 0; i < 4; ++i) {
            ushort4 pk;
            pk.x = __builtin_bit_cast(unsigned short, (__bf16)acc[i][0]);
            pk.y = __builtin_bit_cast(unsigned short, (__bf16)acc[i][1]);
            pk.z = __builtin_bit_cast(unsigned short, (__bf16)acc[i][2]);
            pk.w = __builtin_bit_cast(unsigned short, (__bf16)acc[i][3]);
            *reinterpret_cast<ushort4*>(V2 + (size_t)(h * HDIM + d0 + i) * NKEY + m * NTOK + ng2) = pk;
        }
    } else {
        const float sc = (t == 0) ? QSC : 1.0f;
        unsigned short* base = ((t == 0) ? Qb : Kb)
            + (((size_t)(m * NHD + h)) * NTOK + ng) * HDIM + d0;
        #pragma unroll
        for (int j = 0; j < 4; ++j) {
            unsigned short* row = base + (size_t)j * HDIM;
            *reinterpret_cast<unsigned int*>(row)     = pkbf(acc[0][j] * sc, acc[1][j] * sc);
            *reinterpret_cast<unsigned int*>(row + 2) = pkbf(acc[2][j] * sc, acc[3][j] * sc);
        }
    }
}

// ---------------------------------------------------------------------------
// Kernel 2: MFMA cross-modal attention, 864 blocks x 4 waves (256 thr).
// Block = (h, ko, qb 0..107); wave w: qslot=w&1 (qtile=qb*2+qslot),
// ks=w>>1 (key stream, modality km=2ko+ks).
// R7-style loop (compiler-managed): STAGE(t+1) -> compute(t) -> syncthreads.
// Swizzles (bank-enumerated, conflict-free): K chunk ^= (key>>1)&3,
// V chunk ^= d&7; pre-applied on glds SOURCE, involution on ds_read.
// VALU diet: hoisted zero accumulator (no per-tile v_mov inits); softmax
// denominator via MFMA with ones-B (s_acc) -- consistent with bf16 P and
// moves the row-sum onto the idle matrix pipe. Max-free exp2 softmax.
// Epilogue: ks-combine in padded LDS [64][33] (s in column 32), transpose.
// ---------------------------------------------------------------------------
__global__ __launch_bounds__(256, 4) void attn_kernel(
    const unsigned short* __restrict__ Qb, const unsigned short* __restrict__ Kb,
    const unsigned short* __restrict__ V2,
    float* __restrict__ accT, float* __restrict__ sR)
{
    __shared__ __align__(16) unsigned short smAll[2][2][2][2048]; // [buf][ks][K/V] 32 KB

    const int tid  = threadIdx.x;
    const int lane = tid & 63;
    const int w    = tid >> 6;        // 0..3
    const int qslot = w & 1;
    const int ks    = w >> 1;
    const int l31  = lane & 31;
    const int hi   = lane >> 5;

    const int bid  = blockIdx.x;
    const int slot = bid & 7;              // XCD slot
    const int h    = slot >> 1;
    const int ko   = slot & 1;
    const int qb   = bid >> 3;             // 0..107
    const int qtile = qb * 2 + qslot;      // 0..215
    const int qg0  = qtile * 32;
    const int im   = qg0 / NTOK;
    const int n0   = qg0 % NTOK;
    const int km   = ko * 2 + ks;

    // Q fragments (pre-scaled by QSC)
    const unsigned short* qp = Qb + (((size_t)(im * NHD + h)) * NTOK + n0 + l31) * HDIM + hi * 8;
    const bf16x8 qf0 = ldb8(qp);
    const bf16x8 qf1 = ldb8(qp + 16);

    // --- staging sources (this wave's 4 glds per tile, inverse-swizzled) ---
    const int rk0 = qslot * 32 + (lane >> 2);
    const int ck0 = (lane & 3) ^ ((rk0 >> 1) & 3);
    const unsigned short* gk0 = Kb + (((size_t)(km * NHD + h)) * NTOK + rk0) * HDIM + ck0 * 8;
    const int rk1 = rk0 + 16;
    const int ck1 = (lane & 3) ^ ((rk1 >> 1) & 3);
    const unsigned short* gk1 = Kb + (((size_t)(km * NHD + h)) * NTOK + rk1) * HDIM + ck1 * 8;
    const int dv0 = qslot * 16 + (lane >> 3);
    const int cv0 = (lane & 7) ^ (dv0 & 7);
    const unsigned short* gv0 = V2 + ((size_t)(h * HDIM + dv0)) * NKEY + km * NTOK + cv0 * 8;
    const int dv1 = dv0 + 8;
    const int cv1 = (lane & 7) ^ (dv1 & 7);
    const unsigned short* gv1 = V2 + ((size_t)(h * HDIM + dv1)) * NKEY + km * NTOK + cv1 * 8;

    // --- LDS read offsets (shorts), swizzle involution applied ---
    const int f31 = (l31 >> 1) & 3;
    const int kA0 = l31 * 32 + ((hi ^ f31) << 3);
    const int kB0 = l31 * 32 + (((2 + hi) ^ f31) << 3);
    const int vbase = l31 * 64, x7 = l31 & 7;
    const int vo00 = vbase + (((0 + hi) ^ x7) << 3);
    const int vo01 = vbase + (((2 + hi) ^ x7) << 3);
    const int vo10 = vbase + (((4 + hi) ^ x7) << 3);
    const int vo11 = vbase + (((6 + hi) ^ x7) << 3);

    f32x16 z;
    #pragma unroll
    for (int r = 0; r < 16; ++r) z[r] = 0.f;
    f32x16 o_acc = z, s_acc = z;
    bf16x8 onesv;
    #pragma unroll
    for (int j = 0; j < 8; ++j) onesv[j] = (__bf16)1.0f;

    // stage next tile into buffer bb (4 glds; pointers advance)
    #define STAGE(bb) do {                                      \
        unsigned short* _k = &smAll[bb][ks][0][0];              \
        glds16(gk0, _k + qslot * 1024);                         \
        glds16(gk1, _k + qslot * 1024 + 512);                   \
        unsigned short* _v = &smAll[bb][ks][1][0];              \
        glds16(gv0, _v + qslot * 1024);                         \
        glds16(gv1, _v + qslot * 1024 + 512);                   \
        gk0 += 2048; gk1 += 2048; gv0 += 64; gv1 += 64;         \
    } while (0)

    STAGE(0);                 // tile 0
    __syncthreads();

    int buf = 0;
    for (int t = 0; t < NT; ++t) {
        if (t + 1 < NT) STAGE(buf ^ 1);
        const unsigned short* Kl = &smAll[buf][ks][0][0];
        const unsigned short* Vl = &smAll[buf][ks][1][0];

        #pragma unroll
        for (int st = 0; st < 2; ++st) {
            bf16x8 k0 = ldb8(Kl + st * 1024 + kA0);
            bf16x8 k1 = ldb8(Kl + st * 1024 + kB0);
            f32x16 c = __builtin_amdgcn_mfma_f32_32x32x16_bf16(k0, qf0, z, 0, 0, 0);
            c = __builtin_amdgcn_mfma_f32_32x32x16_bf16(k1, qf1, c, 0, 0, 0);

            float e[16];
            #pragma unroll
            for (int r = 0; r < 16; ++r) e[r] = EXP2(c[r]);
            bf16x8 pa0, pa1;
            #pragma unroll
            for (int j = 0; j < 8; ++j) { pa0[j] = (__bf16)e[j]; pa1[j] = (__bf16)e[8 + j]; }

            bf16x8 v0 = ldb8(Vl + (st ? vo10 : vo00));
            bf16x8 v1 = ldb8(Vl + (st ? vo11 : vo01));

            o_acc = __builtin_amdgcn_mfma_f32_32x32x16_bf16(pa0, v0, o_acc, 0, 0, 0);
            o_acc = __builtin_amdgcn_mfma_f32_32x32x16_bf16(pa1, v1, o_acc, 0, 0, 0);
            s_acc = __builtin_amdgcn_mfma_f32_32x32x16_bf16(pa0, onesv, s_acc, 0, 0, 0);
            s_acc = __builtin_amdgcn_mfma_f32_32x32x16_bf16(pa1, onesv, s_acc, 0, 0, 0);
        }
        __syncthreads();
        buf ^= 1;
    }
    #undef STAGE

    // --- epilogue: combine ks pair in LDS [64 q][33] (s in col 32) ---
    float* accf = (float*)&smAll[0][0][0][0];    // 64*33*4 = 8.4 KB (reuse)
    if (ks == 1) {
        #pragma unroll
        for (int r = 0; r < 16; ++r) {
            const int qrow = (r & 3) + 8 * (r >> 2) + 4 * hi;
            accf[(qslot * 32 + qrow) * 33 + l31] = o_acc[r];
            if (l31 == 0) accf[(qslot * 32 + qrow) * 33 + 32] = s_acc[r];
        }
    }
    __syncthreads();
    if (ks == 0) {
        #pragma unroll
        for (int r = 0; r < 16; ++r) {
            const int qrow = (r & 3) + 8 * (r >> 2) + 4 * hi;
            accf[(qslot * 32 + qrow) * 33 + l31] += o_acc[r];
            if (l31 == 0) accf[(qslot * 32 + qrow) * 33 + 32] += s_acc[r];
        }
    }
    __syncthreads();
    {
        const int q  = tid & 63;
        const int dq = tid >> 6;      // 0..3
        #pragma unroll
        for (int j = 0; j < 8; ++j) {
            const int d = dq * 8 + j;
            accT[((size_t)((ko * 4 + h) * HDIM + d)) * NKEY + (size_t)qb * 64 + q]
                = accf[q * 33 + d];
        }
        if (tid < 64)
            sR[((size_t)(ko * 4 + h)) * NKEY + (size_t)qb * 64 + tid] = accf[tid * 33 + 32];
    }
}

// ---------------------------------------------------------------------------
// Kernel 3: combine outer key halves + normalize + modality-sum.
// ---------------------------------------------------------------------------
__global__ __launch_bounds__(256) void norm_kernel(
    const float* __restrict__ accT, const float* __restrict__ sR,
    float* __restrict__ fused)
{
    const int idx = blockIdx.x * 256 + threadIdx.x;  // 0 .. 128*1728-1
    const int c = idx / NTOK;
    const int n = idx % NTOK;
    const int h = c >> 5;
    float acc = 0.f;
    #pragma unroll
    for (int imq = 0; imq < MODS; ++imq) {
        const size_t q = (size_t)imq * NTOK + n;
        const float s = sR[(size_t)h * NKEY + q] + sR[(size_t)(4 + h) * NKEY + q];
        const float a = accT[(size_t)c * NKEY + q] + accT[(size_t)(c + 128) * NKEY + q];
        acc = fmaf(a, 1.0f / s, acc);
    }
    fused[idx] = acc;
}

// ---------------------------------------------------------------------------
// Kernel 4: out-proj (Wout @ fused) + BatchNorm(eval) + ReLU, 2 tokens/thread
// ---------------------------------------------------------------------------
__global__ __launch_bounds__(256) void outproj_kernel(
    const float* __restrict__ fused, const float* __restrict__ Wout,
    const float* __restrict__ gamma, const float* __restrict__ beta,
    const float* __restrict__ mean,  const float* __restrict__ var,
    float* __restrict__ out)
{
    const int idx = blockIdx.x * 256 + threadIdx.x;  // 0 .. 128*864-1
    const int n2 = idx % (NTOK / 2);
    const int o  = idx / (NTOK / 2);
    const float* W     = Wout + (size_t)o * CH;
    const float* fbase = fused + n2 * 2;
    float a0 = 0.f, a1 = 0.f;
    #pragma unroll 8
    for (int c = 0; c < CH; c += 4) {
        float4 w4 = *reinterpret_cast<const float4*>(W + c);
        float2 r0 = *reinterpret_cast<const float2*>(fbase + (size_t)(c + 0) * NTOK);
        float2 r1 = *reinterpret_cast<const float2*>(fbase + (size_t)(c + 1) * NTOK);
        float2 r2 = *reinterpret_cast<const float2*>(fbase + (size_t)(c + 2) * NTOK);
        float2 r3 = *reinterpret_cast<const float2*>(fbase + (size_t)(c + 3) * NTOK);
        a0 = fmaf(w4.x, r0.x, a0); a0 = fmaf(w4.y, r1.x, a0);
        a0 = fmaf(w4.z, r2.x, a0); a0 = fmaf(w4.w, r3.x, a0);
        a1 = fmaf(w4.x, r0.y, a1); a1 = fmaf(w4.y, r1.y, a1);
        a1 = fmaf(w4.z, r2.y, a1); a1 = fmaf(w4.w, r3.y, a1);
    }
    float inv = gamma[o] * rsqrtf(var[o] + 1e-5f);
    float sh  = fmaf(-mean[o], inv, beta[o]);
    float2 y;
    y.x = fmaxf(fmaf(a0, inv, sh), 0.f);
    y.y = fmaxf(fmaf(a1, inv, sh), 0.f);
    *reinterpret_cast<float2*>(out + (size_t)o * NTOK + n2 * 2) = y;
}

// ---------------------------------------------------------------------------
extern "C" void kernel_launch(void* const* d_in, const int* in_sizes, int n_in,
                              void* d_out, int out_size, void* d_ws, size_t ws_size,
                              hipStream_t stream)
{
    const float* f0    = (const float*)d_in[0];
    const float* f1    = (const float*)d_in[1];
    const float* f2    = (const float*)d_in[2];
    const float* f3    = (const float*)d_in[3];
    const float* Wq    = (const float*)d_in[4];
    const float* Wk    = (const float*)d_in[5];
    const float* Wv    = (const float*)d_in[6];
    const float* Wout  = (const float*)d_in[7];
    const float* gamma = (const float*)d_in[8];
    const float* beta  = (const float*)d_in[9];
    const float* mean  = (const float*)d_in[10];
    const float* var   = (const float*)d_in[11];
    float* out = (float*)d_out;

    const size_t QKV = (size_t)MODS * NHD * NTOK * HDIM;   // 884736 elems
    unsigned short* Qb = (unsigned short*)d_ws;
    unsigned short* Kb = Qb + QKV;
    unsigned short* V2 = Kb + QKV;
    float* accT  = (float*)(V2 + QKV);          // [256 rows][6912 q] f32
    float* sR    = accT + (size_t)2 * NHD * HDIM * NKEY;   // [8][6912]
    float* fused = sR + (size_t)2 * NHD * NKEY;            // [CH][NTOK]

    proj_kernel<<<648, 256, 0, stream>>>(f0, f1, f2, f3, Wq, Wk, Wv, Qb, Kb, V2);
    attn_kernel<<<864, 256, 0, stream>>>(Qb, Kb, V2, accT, sR);
    norm_kernel<<<(CH * NTOK) / 256, 256, 0, stream>>>(accT, sR, fused);
    outproj_kernel<<<(CH * NTOK / 2) / 256, 256, 0, stream>>>(
        fused, Wout, gamma, beta, mean, var, out);
}